// Round 3
// baseline (950.864 us; speedup 1.0000x reference)
//
#include <hip/hip_runtime.h>

typedef unsigned short ushort_t;
typedef __attribute__((ext_vector_type(8))) short   short8_t;
typedef __attribute__((ext_vector_type(4))) float   float4_t;
typedef __attribute__((ext_vector_type(4))) unsigned short ushort4_t;

__device__ __forceinline__ ushort_t f2b(float f) {
    unsigned int u = __float_as_uint(f);
    u += 0x7FFFu + ((u >> 16) & 1u);      // round-to-nearest-even
    return (ushort_t)(u >> 16);
}
__device__ __forceinline__ float b2f(ushort_t s) {
    return __uint_as_float(((unsigned int)s) << 16);
}
__device__ __forceinline__ float frcp(float x) { return __builtin_amdgcn_rcpf(x); }
__device__ __forceinline__ float sigf(float x) { return frcp(1.f + __expf(-x)); }
__device__ __forceinline__ float tanhf_fast(float x) {
    return 1.f - 2.f * frcp(__expf(2.f * x) + 1.f);
}

// ---------------- weight convert: fp32 -> bf16 fragment-order ----------------
// (round-0 proven version, verbatim)
// ws (ushort): [0,196608): rec frags ((m*16+tn)*8+kf)*512 + lane*8 + j
//              [196608, 344064): in frags ((m*16+tn)*6+kf)*512 + lane*8 + j
__global__ void cvt_w(const float* __restrict__ ffr, const float* __restrict__ gr,
                      const float* __restrict__ tr,  const float* __restrict__ ffi,
                      const float* __restrict__ gi,  const float* __restrict__ ti,
                      ushort_t* __restrict__ o)
{
    int i = blockIdx.x * 256 + threadIdx.x;   // exactly [0, 344064)
    float v;
    if (i < 196608) {
        int j    = i & 7;
        int lane = (i >> 3) & 63;
        int kf   = (i >> 9) & 7;
        int tn   = (i >> 12) & 15;
        int m    = i >> 16;
        int col  = tn*16 + (lane & 15);
        int k    = kf*32 + (lane >> 4)*8 + j;
        const float* W = (m == 0) ? ffr : (m == 1) ? gr : tr;
        v = W[(col << 8) + k];
    } else {
        int f    = i - 196608;
        int j    = f & 7;
        int lane = (f >> 3) & 63;
        int q    = f >> 9;            // [0,288) = (m*16+tn)*6+kf
        int kf   = q % 6;
        int tt   = q / 6;
        int tn   = tt & 15;
        int m    = tt >> 4;
        int col  = tn*16 + (lane & 15);
        int k    = kf*32 + (lane >> 4)*8 + j;
        const float* W = (m == 0) ? ffi : (m == 1) ? gi : ti;
        v = W[col*192 + k];
    }
    o[i] = f2b(v);
}

// ---------------- fused LTC kernel ----------------
// Round-0 proven structure (layouts, staging schedule, epilogue) with ONE
// change: the Pl LDS buffer (proj-result spill) is eliminated. The input
// projection's accumulators pac[2][3][4] (fp32, 96 VGPRs) stay live in
// registers across the 4 recurrent steps; acc init is a register move.
// Requires full unroll of the n-loop and step-loop (all pac indices static —
// runtime-indexed ext_vector arrays go to scratch otherwise).
// LDS: Al [0,12800) (4 t-blocks x [16 rows][200]); Hb [12800,21248)
// (2 x [16][264]). Head reuses smem as fp32 [16][257].
__global__ __launch_bounds__(512, 2) void ltc_fused(
    const float* __restrict__ x,
    const ushort_t* __restrict__ wbf,
    const float* __restrict__ ff_in_b, const float* __restrict__ ff_bias,
    const float* __restrict__ g_in_b,  const float* __restrict__ g_bias,
    const float* __restrict__ t_in_b,  const float* __restrict__ t_bias,
    const float* __restrict__ head_w,  const float* __restrict__ head_b,
    float* __restrict__ out)
{
    __shared__ __align__(16) ushort_t smem[21248];
    ushort_t* Al = smem;                 // 12800 el
    ushort_t* Hb = smem + 12800;         // 8448 el = 2 x 4224

    const int tid   = threadIdx.x;
    const int lane  = tid & 63;
    const int wv    = tid >> 6;
    const int l16   = lane & 15;
    const int l4    = lane >> 4;
    const int bbase = blockIdx.x << 4;

    const ushort_t* recF = wbf;
    const ushort_t* inF  = wbf + 196608;

    const int tn0  = 2*wv;
    const int tn1  = 2*wv + 1;
    const int col0 = 32*wv + l16;        // n=0 col (for bias/epilogue)
    const int col1 = col0 + 16;          // n=1 col

    // resident rec-weight B-fragments, coalesced loads (base + lane*16B)
    short8_t wr01[2][2][8];              // m=0,1 : 128 regs
    short8_t wr2[2][4];                  // m=2, kf 0..3 : 32 regs
#pragma unroll
    for (int m = 0; m < 2; ++m)
#pragma unroll
        for (int n = 0; n < 2; ++n) {
            const int tn = n ? tn1 : tn0;
#pragma unroll
            for (int k = 0; k < 8; ++k)
                wr01[m][n][k] = *(const short8_t*)(
                    recF + (((m*16 + tn)*8 + k) << 9) + lane*8);
        }
#pragma unroll
    for (int n = 0; n < 2; ++n) {
        const int tn = n ? tn1 : tn0;
#pragma unroll
        for (int k = 0; k < 4; ++k)
            wr2[n][k] = *(const short8_t*)(
                recF + (((32 + tn)*8 + k) << 9) + lane*8);
    }

    // combined biases: per-thread constant, hoisted out of the chunk loop
    float bs[3][2];
#pragma unroll
    for (int n = 0; n < 2; ++n) {
        const int col = n ? col1 : col0;
        bs[0][n] = ff_in_b[col] + ff_bias[col];
        bs[1][n] = g_in_b[col]  + g_bias[col];
        bs[2][n] = t_in_b[col]  + t_bias[col];
    }

    float hp[2][4];
#pragma unroll
    for (int n = 0; n < 2; ++n)
#pragma unroll
        for (int r = 0; r < 4; ++r) hp[n][r] = 0.f;

    for (int i = tid; i < 4224; i += 512) Hb[i] = 0;   // h0 = 0 (buffer 0)

    // stage chunk 0 into Al
#pragma unroll 1
    for (int p = 0; p < 6; ++p) {
        int flat = p*512 + tid;               // [0,3072) float4s
        int w4   = flat & 15;
        int tt   = (flat >> 4) & 3;
        int rest = flat >> 6;                 // b*3 + c
        int c = rest % 3;
        int b = rest / 3;
        const float4_t v = *(const float4_t*)(
            x + (((bbase + b)*3 + c)*4096) + tt*64 + (w4 << 2));
        ushort4_t o;
        o.x = f2b(v.x); o.y = f2b(v.y); o.z = f2b(v.z); o.w = f2b(v.w);
        *(ushort4_t*)(Al + tt*3200 + b*200 + (c << 6) + (w4 << 2)) = o;
    }
    __syncthreads();

#pragma unroll 1
    for (int tc = 0; tc < 16; ++tc) {
        // ======== input projection -> registers (no LDS roundtrip)
        float4_t pac[2][3][4];               // [n][m][t], fp32, stays live
#pragma unroll
        for (int n = 0; n < 2; ++n)
#pragma unroll
            for (int m = 0; m < 3; ++m)
#pragma unroll
                for (int t = 0; t < 4; ++t)
                    pac[n][m][t] = (float4_t){bs[m][n], bs[m][n], bs[m][n], bs[m][n]};
        {
            const ushort_t* wcb = inF + lane*8;
#pragma unroll
            for (int kf = 0; kf < 6; ++kf) {
                short8_t bk[3][2];
#pragma unroll
                for (int m = 0; m < 3; ++m) {
                    bk[m][0] = *(const short8_t*)(wcb + (((m*16 + tn0)*6 + kf) << 9));
                    bk[m][1] = *(const short8_t*)(wcb + (((m*16 + tn1)*6 + kf) << 9));
                }
#pragma unroll
                for (int t = 0; t < 4; ++t) {
                    const short8_t a = *(const short8_t*)(
                        Al + t*3200 + l16*200 + kf*32 + l4*8);
#pragma unroll
                    for (int m = 0; m < 3; ++m) {
                        pac[0][m][t] = __builtin_amdgcn_mfma_f32_16x16x32_bf16(a, bk[m][0], pac[0][m][t], 0, 0, 0);
                        pac[1][m][t] = __builtin_amdgcn_mfma_f32_16x16x32_bf16(a, bk[m][1], pac[1][m][t], 0, 0, 0);
                    }
                }
            }
        }

        // ======== 4 recurrent steps (fully unrolled; 1 barrier each)
#pragma unroll
        for (int t = 0; t < 4; ++t) {
            const int cur = t & 1;           // tc*4 is even
            const int nxt = cur ^ 1;

            __syncthreads();

            // -- issue staging loads early (hidden under MFMA)
            const bool do_stage = (t < 3) && (tc < 15);
            float4_t sv0, sv1;
            int sa0 = 0, sa1 = 0;
            if (do_stage) {
                const int tcn = tc + 1;
#pragma unroll
                for (int q = 0; q < 2; ++q) {
                    int flat = (t*2 + q)*512 + tid;
                    int w4   = flat & 15;
                    int tt   = (flat >> 4) & 3;
                    int rest = flat >> 6;
                    int c = rest % 3;
                    int b = rest / 3;
                    const float4_t v = *(const float4_t*)(
                        x + (((bbase + b)*3 + c)*4096) + (tcn*4 + tt)*64 + (w4 << 2));
                    int ai = tt*3200 + b*200 + (c << 6) + (w4 << 2);
                    if (q == 0) { sv0 = v; sa0 = ai; } else { sv1 = v; sa1 = ai; }
                }
            }

            // -- stream m=2 high-k rec fragments (coalesced; consumed at kk>=4)
            short8_t s0[4], s1[4];
#pragma unroll
            for (int k = 0; k < 4; ++k) {
                s0[k] = *(const short8_t*)(recF + (((32 + tn0)*8 + k + 4) << 9) + lane*8);
                s1[k] = *(const short8_t*)(recF + (((32 + tn1)*8 + k + 4) << 9) + lane*8);
            }

            // -- acc init: free register moves from proj results
            float4_t acc[3][2];
#pragma unroll
            for (int m = 0; m < 3; ++m)
#pragma unroll
                for (int n = 0; n < 2; ++n)
                    acc[m][n] = pac[n][m][t];

            // -- K loop: A from Hb (shared), B resident/streamed
#pragma unroll
            for (int kk = 0; kk < 4; ++kk) {
                const short8_t a = *(const short8_t*)(
                    Hb + cur*4224 + l16*264 + kk*32 + l4*8);
                acc[0][0] = __builtin_amdgcn_mfma_f32_16x16x32_bf16(a, wr01[0][0][kk], acc[0][0], 0, 0, 0);
                acc[0][1] = __builtin_amdgcn_mfma_f32_16x16x32_bf16(a, wr01[0][1][kk], acc[0][1], 0, 0, 0);
                acc[1][0] = __builtin_amdgcn_mfma_f32_16x16x32_bf16(a, wr01[1][0][kk], acc[1][0], 0, 0, 0);
                acc[1][1] = __builtin_amdgcn_mfma_f32_16x16x32_bf16(a, wr01[1][1][kk], acc[1][1], 0, 0, 0);
                acc[2][0] = __builtin_amdgcn_mfma_f32_16x16x32_bf16(a, wr2[0][kk], acc[2][0], 0, 0, 0);
                acc[2][1] = __builtin_amdgcn_mfma_f32_16x16x32_bf16(a, wr2[1][kk], acc[2][1], 0, 0, 0);
            }
#pragma unroll
            for (int kk = 4; kk < 8; ++kk) {
                const short8_t a = *(const short8_t*)(
                    Hb + cur*4224 + l16*264 + kk*32 + l4*8);
                acc[0][0] = __builtin_amdgcn_mfma_f32_16x16x32_bf16(a, wr01[0][0][kk], acc[0][0], 0, 0, 0);
                acc[0][1] = __builtin_amdgcn_mfma_f32_16x16x32_bf16(a, wr01[0][1][kk], acc[0][1], 0, 0, 0);
                acc[1][0] = __builtin_amdgcn_mfma_f32_16x16x32_bf16(a, wr01[1][0][kk], acc[1][0], 0, 0, 0);
                acc[1][1] = __builtin_amdgcn_mfma_f32_16x16x32_bf16(a, wr01[1][1][kk], acc[1][1], 0, 0, 0);
                acc[2][0] = __builtin_amdgcn_mfma_f32_16x16x32_bf16(a, s0[kk-4], acc[2][0], 0, 0, 0);
                acc[2][1] = __builtin_amdgcn_mfma_f32_16x16x32_bf16(a, s1[kk-4], acc[2][1], 0, 0, 0);
            }

            // -- finish staging writes to Al
            if (do_stage) {
                ushort4_t o;
                o.x = f2b(sv0.x); o.y = f2b(sv0.y); o.z = f2b(sv0.z); o.w = f2b(sv0.w);
                *(ushort4_t*)(Al + sa0) = o;
                o.x = f2b(sv1.x); o.y = f2b(sv1.y); o.z = f2b(sv1.z); o.w = f2b(sv1.w);
                *(ushort4_t*)(Al + sa1) = o;
            }

            // -- epilogue: C element (row=l4*4+r [batch], col [hidden])
#pragma unroll
            for (int n = 0; n < 2; ++n) {
                const int col = n ? col1 : col0;
#pragma unroll
                for (int r = 0; r < 4; ++r) {
                    const float h   = hp[n][r];
                    const float cd  = tanhf_fast(acc[0][n][r]);
                    const float g   = sigf(acc[1][n][r]);
                    const float tau = 0.5f + 1.5f * sigf(acc[2][n][r]);
                    const float hn  = tanhf_fast(h + (g*cd - h) * frcp(tau));
                    hp[n][r] = hn;
                    Hb[nxt*4224 + (l4*4 + r)*264 + col] = f2b(hn);
                }
            }
        }
    }
    __syncthreads();

    // ---- head: out[b,o] = sum_j h[b,j]*head_w[o,j] + head_b[o]
    float* hf = (float*)smem;                // [16][257] fp32 (Al/Hb dead)
#pragma unroll
    for (int n = 0; n < 2; ++n) {
        const int col = n ? col1 : col0;
#pragma unroll
        for (int r = 0; r < 4; ++r)
            hf[(l4*4 + r)*257 + col] = hp[n][r];
    }
    __syncthreads();
    if (tid < 160) {
        const int r = tid / 10;
        const int o = tid - r*10;
        float s = head_b[o];
        const float* wrow = head_w + o*256;
        const float* hrow = hf + r*257;
#pragma unroll 8
        for (int j = 0; j < 256; ++j) s += hrow[j] * wrow[j];
        out[bbase*10 + tid] = s;
    }
}

extern "C" void kernel_launch(void* const* d_in, const int* in_sizes, int n_in,
                              void* d_out, int out_size, void* d_ws, size_t ws_size,
                              hipStream_t stream)
{
    const float* x     = (const float*)d_in[0];
    const float* ffi_w = (const float*)d_in[1];
    const float* ffi_b = (const float*)d_in[2];
    const float* ffr_w = (const float*)d_in[3];
    const float* ff_bs = (const float*)d_in[4];
    const float* gi_w  = (const float*)d_in[5];
    const float* gi_b  = (const float*)d_in[6];
    const float* gr_w  = (const float*)d_in[7];
    const float* g_bs  = (const float*)d_in[8];
    const float* ti_w  = (const float*)d_in[9];
    const float* ti_b  = (const float*)d_in[10];
    const float* tr_w  = (const float*)d_in[11];
    const float* t_bs  = (const float*)d_in[12];
    const float* hw    = (const float*)d_in[13];
    const float* hb    = (const float*)d_in[14];

    ushort_t* ws = (ushort_t*)d_ws;   // needs 688128 bytes

    cvt_w<<<1344, 256, 0, stream>>>(ffr_w, gr_w, tr_w, ffi_w, gi_w, ti_w, ws);
    ltc_fused<<<256, 512, 0, stream>>>(x, ws, ffi_b, ff_bs, gi_b, g_bs,
                                       ti_b, t_bs, hw, hb, (float*)d_out);
}

// Round 4
// 609.711 us; speedup vs baseline: 1.5595x; 1.5595x over previous
//
#include <hip/hip_runtime.h>

typedef unsigned short ushort_t;
typedef __attribute__((ext_vector_type(8))) short   short8_t;
typedef __attribute__((ext_vector_type(4))) float   float4_t;
typedef __attribute__((ext_vector_type(4))) unsigned short ushort4_t;

__device__ __forceinline__ ushort_t f2b(float f) {
    unsigned int u = __float_as_uint(f);
    u += 0x7FFFu + ((u >> 16) & 1u);      // round-to-nearest-even
    return (ushort_t)(u >> 16);
}
__device__ __forceinline__ float b2f(ushort_t s) {
    return __uint_as_float(((unsigned int)s) << 16);
}
__device__ __forceinline__ float frcp(float x) { return __builtin_amdgcn_rcpf(x); }
__device__ __forceinline__ float sigf(float x) { return frcp(1.f + __expf(-x)); }
__device__ __forceinline__ float tanhf_fast(float x) {
    return 1.f - 2.f * frcp(__expf(2.f * x) + 1.f);
}

// ---------------- weight convert: fp32 -> bf16 fragment-order ----------------
// Round-2 proven version: one thread produces one 8-ushort lane-fragment
// (2x float4 read, 16B contiguous store). Output layout identical to the
// original: rec frags ((m*16+tn)*8+kf)*512 + lane*8 + j at [0,196608);
// in frags ((m*16+tn)*6+kf)*512 + lane*8 + j at [196608,344064).
__global__ void cvt_w(const float* __restrict__ ffr, const float* __restrict__ gr,
                      const float* __restrict__ tr,  const float* __restrict__ ffi,
                      const float* __restrict__ gi,  const float* __restrict__ ti,
                      ushort_t* __restrict__ o)
{
    int f = blockIdx.x * 256 + threadIdx.x;   // [0, 43008) = 344064/8
    const float* W;
    int src;
    if (f < 24576) {                           // rec frags
        int lane = f & 63;
        int kf   = (f >> 6) & 7;
        int tn   = (f >> 9) & 15;
        int m    = f >> 13;
        int col  = tn*16 + (lane & 15);
        int k0   = kf*32 + (lane >> 4)*8;
        W = (m == 0) ? ffr : (m == 1) ? gr : tr;
        src = (col << 8) + k0;
    } else {                                   // in frags
        int g    = f - 24576;
        int lane = g & 63;
        int q    = g >> 6;                     // (m*16+tn)*6+kf
        int kf   = q % 6;
        int tt   = q / 6;
        int tn   = tt & 15;
        int m    = tt >> 4;
        int col  = tn*16 + (lane & 15);
        int k0   = kf*32 + (lane >> 4)*8;
        W = (m == 0) ? ffi : (m == 1) ? gi : ti;
        src = col*192 + k0;
    }
    const float4_t v0 = *(const float4_t*)(W + src);
    const float4_t v1 = *(const float4_t*)(W + src + 4);
    ushort4_t a, b;
    a.x = f2b(v0.x); a.y = f2b(v0.y); a.z = f2b(v0.z); a.w = f2b(v0.w);
    b.x = f2b(v1.x); b.y = f2b(v1.y); b.z = f2b(v1.z); b.w = f2b(v1.w);
    *(ushort4_t*)(o + (f << 3))     = a;
    *(ushort4_t*)(o + (f << 3) + 4) = b;
}

// ---------------- fused LTC kernel ----------------
// Round-0 proven structure (595us / 401us dispatch). Three register-safe trims:
//  (1) staging address scalarization: flat>>6 == 8*(2t+q)+wv (wave-uniform)
//      -> readfirstlane puts the /3 %3 and row-base math on the SALU.
//  (2) acc zero-init + late Pl add: first MFMA after the barrier no longer
//      drains the 6 Pl ds_reads (in-order lgkmcnt); Pl raw read after K-loop
//      (latency covered by trailing MFMAs), added in the epilogue.
//  (3) m2-hi stream loads issued before staging loads (consumed earlier).
// Everything else verbatim: LDS layouts, schedule, epilogue math, head.
__global__ __launch_bounds__(512, 2) void ltc_fused(
    const float* __restrict__ x,
    const ushort_t* __restrict__ wbf,
    const float* __restrict__ ff_in_b, const float* __restrict__ ff_bias,
    const float* __restrict__ g_in_b,  const float* __restrict__ g_bias,
    const float* __restrict__ t_in_b,  const float* __restrict__ t_bias,
    const float* __restrict__ head_w,  const float* __restrict__ head_b,
    float* __restrict__ out)
{
    __shared__ __align__(16) ushort_t smem[70400];
    ushort_t* Al = smem;                 // 12800 el
    ushort_t* Pl = smem + 12800;         // 49152 el
    ushort_t* Hb = smem + 61952;         // 8448 el = 2 x 4224

    const int tid   = threadIdx.x;
    const int lane  = tid & 63;
    const int wv    = tid >> 6;
    const int l16   = lane & 15;
    const int l4    = lane >> 4;
    const int bbase = blockIdx.x << 4;
    const int w4s   = tid & 15;          // staging: flat&15 == tid&15
    const int tts   = (tid >> 4) & 3;    // staging: (flat>>4)&3 == (tid>>4)&3

    const ushort_t* recF = wbf;
    const ushort_t* inF  = wbf + 196608;

    const int tn0  = 2*wv;
    const int tn1  = 2*wv + 1;
    const int col0 = 32*wv + l16;        // n=0 col (for bias/epilogue)
    const int col1 = col0 + 16;          // n=1 col

    // resident rec-weight B-fragments, coalesced loads (base + lane*16B)
    short8_t wr01[2][2][8];              // m=0,1 : 128 regs
    short8_t wr2[2][4];                  // m=2, kf 0..3 : 32 regs
#pragma unroll
    for (int m = 0; m < 2; ++m)
#pragma unroll
        for (int n = 0; n < 2; ++n) {
            const int tn = n ? tn1 : tn0;
#pragma unroll
            for (int k = 0; k < 8; ++k)
                wr01[m][n][k] = *(const short8_t*)(
                    recF + (((m*16 + tn)*8 + k) << 9) + lane*8);
        }
#pragma unroll
    for (int n = 0; n < 2; ++n) {
        const int tn = n ? tn1 : tn0;
#pragma unroll
        for (int k = 0; k < 4; ++k)
            wr2[n][k] = *(const short8_t*)(
                recF + (((32 + tn)*8 + k) << 9) + lane*8);
    }

    float hp[2][4];
#pragma unroll
    for (int n = 0; n < 2; ++n)
#pragma unroll
        for (int r = 0; r < 4; ++r) hp[n][r] = 0.f;

    for (int i = tid; i < 4224; i += 512) Hb[i] = 0;   // h0 = 0 (buffer 0)

    // stage chunk 0 into Al (scalarized row math: rest = 8p + wv, uniform)
#pragma unroll 1
    for (int p = 0; p < 6; ++p) {
        int rest = __builtin_amdgcn_readfirstlane(8*p + wv);
        int c = rest % 3;
        int b = rest / 3;
        const float4_t v = *(const float4_t*)(
            x + (((bbase + b)*3 + c)*4096) + tts*64 + (w4s << 2));
        ushort4_t o;
        o.x = f2b(v.x); o.y = f2b(v.y); o.z = f2b(v.z); o.w = f2b(v.w);
        *(ushort4_t*)(Al + tts*3200 + b*200 + (c << 6) + (w4s << 2)) = o;
    }
    __syncthreads();

#pragma unroll 1
    for (int tc = 0; tc < 16; ++tc) {
        // ======== input projection (reads Al; coalesced B frags; own-lane Pl)
#pragma unroll 1
        for (int n = 0; n < 2; ++n) {
            const int tn  = n ? tn1 : tn0;
            const int col = n ? col1 : col0;
            float bs[3];
            bs[0] = ff_in_b[col] + ff_bias[col];
            bs[1] = g_in_b[col]  + g_bias[col];
            bs[2] = t_in_b[col]  + t_bias[col];
            float4_t pac[3][4];
#pragma unroll
            for (int m = 0; m < 3; ++m)
#pragma unroll
                for (int t = 0; t < 4; ++t)
                    pac[m][t] = (float4_t){bs[m], bs[m], bs[m], bs[m]};
            const ushort_t* wcb = inF + lane*8;
#pragma unroll
            for (int kf = 0; kf < 6; ++kf) {
                const short8_t bk0 = *(const short8_t*)(wcb + (((     tn)*6 + kf) << 9));
                const short8_t bk1 = *(const short8_t*)(wcb + (((16 + tn)*6 + kf) << 9));
                const short8_t bk2 = *(const short8_t*)(wcb + (((32 + tn)*6 + kf) << 9));
#pragma unroll
                for (int t = 0; t < 4; ++t) {
                    const short8_t a = *(const short8_t*)(
                        Al + t*3200 + l16*200 + kf*32 + l4*8);
                    pac[0][t] = __builtin_amdgcn_mfma_f32_16x16x32_bf16(a, bk0, pac[0][t], 0, 0, 0);
                    pac[1][t] = __builtin_amdgcn_mfma_f32_16x16x32_bf16(a, bk1, pac[1][t], 0, 0, 0);
                    pac[2][t] = __builtin_amdgcn_mfma_f32_16x16x32_bf16(a, bk2, pac[2][t], 0, 0, 0);
                }
            }
#pragma unroll
            for (int m = 0; m < 3; ++m)
#pragma unroll
                for (int t = 0; t < 4; ++t) {
                    ushort4_t o;
                    o.x = f2b(pac[m][t].x); o.y = f2b(pac[m][t].y);
                    o.z = f2b(pac[m][t].z); o.w = f2b(pac[m][t].w);
                    *(ushort4_t*)(Pl + ((((t*8 + wv)*3 + m)*2 + n) << 8) + (lane << 2)) = o;
                }
        }

        // ======== 4 recurrent steps (1 barrier each)
#pragma unroll 1
        for (int t = 0; t < 4; ++t) {
            const int step = tc*4 + t;
            const int cur = step & 1;
            const int nxt = cur ^ 1;

            __syncthreads();

            // -- stream m=2 high-k rec fragments first (consumed at kk>=4)
            short8_t s0[4], s1[4];
#pragma unroll
            for (int k = 0; k < 4; ++k) {
                s0[k] = *(const short8_t*)(recF + (((32 + tn0)*8 + k + 4) << 9) + lane*8);
                s1[k] = *(const short8_t*)(recF + (((32 + tn1)*8 + k + 4) << 9) + lane*8);
            }

            // -- issue staging loads early (hidden under MFMA); scalar row math
            const bool do_stage = (t < 3) && (tc < 15);
            float4_t sv0, sv1;
            int sa0 = 0, sa1 = 0;
            if (do_stage) {
                const int tcn = tc + 1;
#pragma unroll
                for (int q = 0; q < 2; ++q) {
                    int rest = __builtin_amdgcn_readfirstlane(8*(t*2 + q) + wv);
                    int c = rest % 3;
                    int b = rest / 3;
                    const float4_t v = *(const float4_t*)(
                        x + (((bbase + b)*3 + c)*4096) + (tcn*4 + tts)*64 + (w4s << 2));
                    int ai = tts*3200 + b*200 + (c << 6) + (w4s << 2);
                    if (q == 0) { sv0 = v; sa0 = ai; } else { sv1 = v; sa1 = ai; }
                }
            }

            // -- acc starts at zero: first MFMA has no LDS dependency on C
            float4_t acc[3][2];
#pragma unroll
            for (int m = 0; m < 3; ++m)
#pragma unroll
                for (int n = 0; n < 2; ++n)
                    acc[m][n] = (float4_t){0.f, 0.f, 0.f, 0.f};

            // -- K loop: A from Hb (shared), B resident/streamed
#pragma unroll
            for (int kk = 0; kk < 4; ++kk) {
                const short8_t a = *(const short8_t*)(
                    Hb + cur*4224 + l16*264 + kk*32 + l4*8);
                acc[0][0] = __builtin_amdgcn_mfma_f32_16x16x32_bf16(a, wr01[0][0][kk], acc[0][0], 0, 0, 0);
                acc[0][1] = __builtin_amdgcn_mfma_f32_16x16x32_bf16(a, wr01[0][1][kk], acc[0][1], 0, 0, 0);
                acc[1][0] = __builtin_amdgcn_mfma_f32_16x16x32_bf16(a, wr01[1][0][kk], acc[1][0], 0, 0, 0);
                acc[1][1] = __builtin_amdgcn_mfma_f32_16x16x32_bf16(a, wr01[1][1][kk], acc[1][1], 0, 0, 0);
                acc[2][0] = __builtin_amdgcn_mfma_f32_16x16x32_bf16(a, wr2[0][kk], acc[2][0], 0, 0, 0);
                acc[2][1] = __builtin_amdgcn_mfma_f32_16x16x32_bf16(a, wr2[1][kk], acc[2][1], 0, 0, 0);
            }
#pragma unroll
            for (int kk = 4; kk < 8; ++kk) {
                const short8_t a = *(const short8_t*)(
                    Hb + cur*4224 + l16*264 + kk*32 + l4*8);
                acc[0][0] = __builtin_amdgcn_mfma_f32_16x16x32_bf16(a, wr01[0][0][kk], acc[0][0], 0, 0, 0);
                acc[0][1] = __builtin_amdgcn_mfma_f32_16x16x32_bf16(a, wr01[0][1][kk], acc[0][1], 0, 0, 0);
                acc[1][0] = __builtin_amdgcn_mfma_f32_16x16x32_bf16(a, wr01[1][0][kk], acc[1][0], 0, 0, 0);
                acc[1][1] = __builtin_amdgcn_mfma_f32_16x16x32_bf16(a, wr01[1][1][kk], acc[1][1], 0, 0, 0);
                acc[2][0] = __builtin_amdgcn_mfma_f32_16x16x32_bf16(a, s0[kk-4], acc[2][0], 0, 0, 0);
                acc[2][1] = __builtin_amdgcn_mfma_f32_16x16x32_bf16(a, s1[kk-4], acc[2][1], 0, 0, 0);
            }

            // -- read proj results late (latency covered by trailing MFMAs)
            ushort4_t praw[3][2];
#pragma unroll
            for (int m = 0; m < 3; ++m)
#pragma unroll
                for (int n = 0; n < 2; ++n)
                    praw[m][n] = *(const ushort4_t*)(
                        Pl + ((((t*8 + wv)*3 + m)*2 + n) << 8) + (lane << 2));

            // -- finish staging writes to Al
            if (do_stage) {
                ushort4_t o;
                o.x = f2b(sv0.x); o.y = f2b(sv0.y); o.z = f2b(sv0.z); o.w = f2b(sv0.w);
                *(ushort4_t*)(Al + sa0) = o;
                o.x = f2b(sv1.x); o.y = f2b(sv1.y); o.z = f2b(sv1.z); o.w = f2b(sv1.w);
                *(ushort4_t*)(Al + sa1) = o;
            }

            // -- epilogue: C element (row=l4*4+r [batch], col [hidden])
#pragma unroll
            for (int n = 0; n < 2; ++n) {
                const int col = n ? col1 : col0;
#pragma unroll
                for (int r = 0; r < 4; ++r) {
                    const float a0  = acc[0][n][r] + b2f(praw[0][n][r]);
                    const float a1  = acc[1][n][r] + b2f(praw[1][n][r]);
                    const float a2  = acc[2][n][r] + b2f(praw[2][n][r]);
                    const float h   = hp[n][r];
                    const float cd  = tanhf_fast(a0);
                    const float g   = sigf(a1);
                    const float tau = 0.5f + 1.5f * sigf(a2);
                    const float hn  = tanhf_fast(h + (g*cd - h) * frcp(tau));
                    hp[n][r] = hn;
                    Hb[nxt*4224 + (l4*4 + r)*264 + col] = f2b(hn);
                }
            }
        }
    }
    __syncthreads();

    // ---- head: out[b,o] = sum_j h[b,j]*head_w[o,j] + head_b[o]
    float* hf = (float*)(smem + 12800);      // [16][257] fp32, reuse Pl space
#pragma unroll
    for (int n = 0; n < 2; ++n) {
        const int col = n ? col1 : col0;
#pragma unroll
        for (int r = 0; r < 4; ++r)
            hf[(l4*4 + r)*257 + col] = hp[n][r];
    }
    __syncthreads();
    if (tid < 160) {
        const int r = tid / 10;
        const int o = tid - r*10;
        float s = head_b[o];
        const float* wrow = head_w + o*256;
        const float* hrow = hf + r*257;
#pragma unroll 8
        for (int j = 0; j < 256; ++j) s += hrow[j] * wrow[j];
        out[bbase*10 + tid] = s;
    }
}

extern "C" void kernel_launch(void* const* d_in, const int* in_sizes, int n_in,
                              void* d_out, int out_size, void* d_ws, size_t ws_size,
                              hipStream_t stream)
{
    const float* x     = (const float*)d_in[0];
    const float* ffi_w = (const float*)d_in[1];
    const float* ffi_b = (const float*)d_in[2];
    const float* ffr_w = (const float*)d_in[3];
    const float* ff_bs = (const float*)d_in[4];
    const float* gi_w  = (const float*)d_in[5];
    const float* gi_b  = (const float*)d_in[6];
    const float* gr_w  = (const float*)d_in[7];
    const float* g_bs  = (const float*)d_in[8];
    const float* ti_w  = (const float*)d_in[9];
    const float* ti_b  = (const float*)d_in[10];
    const float* tr_w  = (const float*)d_in[11];
    const float* t_bs  = (const float*)d_in[12];
    const float* hw    = (const float*)d_in[13];
    const float* hb    = (const float*)d_in[14];

    ushort_t* ws = (ushort_t*)d_ws;   // needs 688128 bytes

    cvt_w<<<168, 256, 0, stream>>>(ffr_w, gr_w, tr_w, ffi_w, gi_w, ti_w, ws);
    ltc_fused<<<256, 512, 0, stream>>>(x, ws, ffi_b, ff_bs, gi_b, g_bs,
                                       ti_b, t_bs, hw, hb, (float*)d_out);
}